// Round 3
// baseline (423.390 us; speedup 1.0000x reference)
//
#include <hip/hip_runtime.h>

#define BM 64          // rows per block
#define KC 64          // K chunk staged in LDS
#define DD 2048        // d_model
#define EE 64          // experts
#define NROWS 32768    // 4 * 8192
#define NTILES (DD / KC)   // 32

// LDS: two buffers, each 8192 floats = [x tile 64x64][w tile 64x64], natural
// row-major with a 16B-chunk XOR swizzle: position p of row r holds global
// chunk (p ^ ((r>>2)&15)). Written linearly by global_load_lds from a
// pre-swizzled global source; de-swizzled on the read side with one XOR.
__global__ __launch_bounds__(256) void router_main(const float* __restrict__ x,
                                                   const float* __restrict__ W,
                                                   float* __restrict__ out,
                                                   float* __restrict__ accum) {
    __shared__ __align__(16) float smem[16384];   // 64 KB

    const int t = threadIdx.x;
    const int l = t & 63;
    const int w = t >> 6;          // wave id 0..3
    const int row0 = blockIdx.x * BM;

    const char* xc = (const char*)x;
    const char* wc = (const char*)W;

    // ---- staging address precompute ----
    // load i of wave w: LDS chunk n = i*256 + w*64 + lane  -> row n>>4, pos n&15
    // source global chunk = pos ^ ((row>>2)&15), row>>2 = 4i + w
    unsigned gxb[4], gwb[4];
    int ldsb[4];
#pragma unroll
    for (int i = 0; i < 4; ++i) {
        const int row = i * 16 + w * 4 + (l >> 4);
        const int c   = (l & 15) ^ ((4 * i + w) & 15);
        gxb[i]  = (unsigned)((( (unsigned)(row0 + row) * DD ) + c * 4) * 4);  // bytes
        gwb[i]  = (unsigned)((( (unsigned)row * DD ) + c * 4) * 4);           // bytes
        ldsb[i] = i * 1024 + w * 256;   // floats, wave-uniform
    }

#define STAGE(buf, tile) do {                                                          \
    const unsigned kof_ = (unsigned)(tile) * (KC * 4);                                 \
    float* bx_ = smem + (buf) * 8192;                                                  \
    float* bw_ = bx_ + 4096;                                                           \
    _Pragma("unroll")                                                                  \
    for (int i_ = 0; i_ < 4; ++i_) {                                                   \
        __builtin_amdgcn_global_load_lds(                                              \
            (const __attribute__((address_space(1))) void*)(xc + gxb[i_] + kof_),      \
            (__attribute__((address_space(3))) void*)(bx_ + ldsb[i_]), 16, 0, 0);      \
        __builtin_amdgcn_global_load_lds(                                              \
            (const __attribute__((address_space(1))) void*)(wc + gwb[i_] + kof_),      \
            (__attribute__((address_space(3))) void*)(bw_ + ldsb[i_]), 16, 0, 0);      \
    }                                                                                  \
} while (0)

    // ---- micro-tile mapping: 4 rows x 4 experts per thread ----
    const int tr = t & 15;     // rows 4*tr..4*tr+3   (row>>2 == tr)
    const int tc = t >> 4;     // exps 4*tc..4*tc+3   (exp>>2 == tc)
    const int trm = tr << 2;   // XOR mask in float units (chunk*4)
    const int tcm = tc << 2;

    float acc[4][4] = {};

    int cur = 0;
    STAGE(0, 0);
    __syncthreads();   // drains vmcnt(0) + barrier

    for (int tile = 0; tile < NTILES; ++tile) {
        if (tile + 1 < NTILES) STAGE(cur ^ 1, tile + 1);  // async prefetch

        const float* bx = smem + cur * 8192;
        const float* bw = bx + 4096;
#pragma unroll
        for (int k4 = 0; k4 < 16; ++k4) {
            const int xo = trm ^ (k4 << 2);   // de-swizzle: pos = k4 ^ tr
            const int wo = tcm ^ (k4 << 2);
            float4 xa[4], wv[4];
#pragma unroll
            for (int i = 0; i < 4; ++i)
                xa[i] = *reinterpret_cast<const float4*>(bx + ((4 * tr + i) << 6) + xo);
#pragma unroll
            for (int j = 0; j < 4; ++j)
                wv[j] = *reinterpret_cast<const float4*>(bw + ((4 * tc + j) << 6) + wo);
#pragma unroll
            for (int i = 0; i < 4; ++i)
#pragma unroll
                for (int j = 0; j < 4; ++j) {
                    acc[i][j] = fmaf(xa[i].x, wv[j].x, acc[i][j]);
                    acc[i][j] = fmaf(xa[i].y, wv[j].y, acc[i][j]);
                    acc[i][j] = fmaf(xa[i].z, wv[j].z, acc[i][j]);
                    acc[i][j] = fmaf(xa[i].w, wv[j].w, acc[i][j]);
                }
        }
        __syncthreads();   // drain prefetch vmcnt + all waves done reading cur
        cur ^= 1;
    }

    // ---- epilogue: reuse LDS ----
    float* lg     = smem;           // [64][65]
    float* pm1    = smem + 4160;    // [4][64] partial top-1 val
    float* pi1    = smem + 4416;    // [4][64] partial top-1 idx
    float* pm2    = smem + 4672;    // [4][64]
    float* pi2    = smem + 4928;    // [4][64]
    float* rowm   = smem + 5184;    // [64]
    float* ps     = smem + 5248;    // [4][64] partial exp sums
    float* rowinv = smem + 5504;    // [64]
    float* cpart  = smem + 5568;    // [4][64] partial column sums

#pragma unroll
    for (int i = 0; i < 4; ++i)
#pragma unroll
        for (int j = 0; j < 4; ++j)
            lg[(4 * tr + i) * 65 + 4 * tc + j] = acc[i][j];
    __syncthreads();

    // Phase A: partial top-2 over 16 experts per thread (4 threads per row)
    {
        const int q = t >> 6, r = t & 63;
        float m1 = -INFINITY, m2 = -INFINITY, i1 = 0.f, i2 = 0.f;
        const float* rowp = lg + r * 65 + q * 16;
        for (int e = 0; e < 16; ++e) {
            const float v = rowp[e];
            if (v > m1)      { m2 = m1; i2 = i1; m1 = v; i1 = (float)(q * 16 + e); }
            else if (v > m2) { m2 = v; i2 = (float)(q * 16 + e); }
        }
        pm1[q * 64 + r] = m1; pi1[q * 64 + r] = i1;
        pm2[q * 64 + r] = m2; pi2[q * 64 + r] = i2;
    }
    __syncthreads();

    // Phase B: merge partials (index-ascending -> ties keep lowest index),
    // top-2 softmax, write probs + indices
    if (t < 64) {
        const int r = t;
        float m1 = pm1[r], m2 = pm2[r], i1 = pi1[r], i2 = pi2[r];
        for (int q = 1; q < 4; ++q) {
            const float b1 = pm1[q * 64 + r], b2 = pm2[q * 64 + r];
            const float bi1 = pi1[q * 64 + r], bi2 = pi2[q * 64 + r];
            if (b1 > m1) {
                if (m1 >= b2) { m2 = m1; i2 = i1; }
                else          { m2 = b2; i2 = bi2; }
                m1 = b1; i1 = bi1;
            } else if (b1 > m2) { m2 = b1; i2 = bi1; }
        }
        rowm[r] = m1;
        const float e2  = __expf(m2 - m1);
        const float inv = 1.0f / (1.0f + e2);
        const size_t gr = (size_t)row0 + r;
        out[2 * gr]     = inv;
        out[2 * gr + 1] = e2 * inv;
        out[2 * (size_t)NROWS + 2 * gr]     = i1;
        out[2 * (size_t)NROWS + 2 * gr + 1] = i2;
    }
    __syncthreads();

    // Phase C: partial exp-sums, stash exp() back into lg
    {
        const int q = t >> 6, r = t & 63;
        const float m = rowm[r];
        float s = 0.f;
        float* rowp = lg + r * 65 + q * 16;
        for (int e = 0; e < 16; ++e) {
            const float p = __expf(rowp[e] - m);
            rowp[e] = p;
            s += p;
        }
        ps[q * 64 + r] = s;
    }
    __syncthreads();

    // Phase D: row inverse sums
    if (t < 64) rowinv[t] = 1.0f / (ps[t] + ps[64 + t] + ps[128 + t] + ps[192 + t]);
    __syncthreads();

    // Phase E: partial column sums of router probs (16 rows per thread)
    {
        const int e = t & 63, q = t >> 6;
        float cs = 0.f;
        for (int rr = q * 16; rr < q * 16 + 16; ++rr)
            cs += lg[rr * 65 + e] * rowinv[rr];
        cpart[q * 64 + e] = cs;
    }
    __syncthreads();

    // Phase F: one atomic per expert per block
    if (t < 64)
        atomicAdd(&accum[t], cpart[t] + cpart[64 + t] + cpart[128 + t] + cpart[192 + t]);
#undef STAGE
}

// ---------------------------------------------------------------------------
// Finisher: expert_probs = accum / NROWS; lb_loss = .01 * sum(p*log(p+1e-8))
// ---------------------------------------------------------------------------
__global__ void router_loss(const float* __restrict__ accum, float* __restrict__ out) {
    const int e = threadIdx.x;  // 64 threads = 1 wave
    const float p = accum[e] * (1.0f / (float)NROWS);
    float v = p * __logf(p + 1e-8f);
#pragma unroll
    for (int off = 32; off > 0; off >>= 1) v += __shfl_down(v, off);
    if (e == 0) out[4 * (size_t)NROWS] = 0.01f * v;
}

extern "C" void kernel_launch(void* const* d_in, const int* in_sizes, int n_in,
                              void* d_out, int out_size, void* d_ws, size_t ws_size,
                              hipStream_t stream) {
    const float* x = (const float*)d_in[0];
    const float* W = (const float*)d_in[1];
    float* out = (float*)d_out;
    float* accum = (float*)d_ws;

    hipMemsetAsync(d_ws, 0, EE * sizeof(float), stream);
    router_main<<<NROWS / BM, 256, 0, stream>>>(x, W, out, accum);
    router_loss<<<1, 64, 0, stream>>>(accum, out);
}